// Round 3
// baseline (1161.760 us; speedup 1.0000x reference)
//
#include <hip/hip_runtime.h>
#include <hip/hip_bf16.h>

typedef unsigned short u16;
typedef unsigned int u32;
typedef __attribute__((ext_vector_type(8))) __bf16 bf16x8;
typedef __attribute__((ext_vector_type(16))) float f32x16;

#define N_TOK 4096
#define DIMF  514
#define KPAD  544      // 17*32, zero-padded K for QKV gemm
#define OUT3  768
#define OUTD  256
#define RDIM  512
#define FDIM  1542
#define SHIFT 16.0f
#define NCHUNK 4       // split-K chunks over the 4096 keys

__device__ __forceinline__ bf16x8 ld_frag(const u16* p) {
    return __builtin_bit_cast(bf16x8, *reinterpret_cast<const uint4*>(p));
}
__device__ __forceinline__ u16 f2bf(float x) {
    return __builtin_bit_cast(u16, __float2bfloat16(x));
}
__device__ __forceinline__ float bf2f(u16 u) {
    return __bfloat162float(__builtin_bit_cast(__hip_bfloat16, u));
}
__device__ __forceinline__ f32x16 mfma_b(bf16x8 a, bf16x8 b, f32x16 c) {
    return __builtin_amdgcn_mfma_f32_32x32x16_bf16(a, b, c, 0, 0, 0);
}

// ---------------------------------------------------------------- prep
__global__ void prep_kernel(const float* __restrict__ t1, const float* __restrict__ t2,
                            const float* __restrict__ t1c,
                            const float* __restrict__ W1, const float* __restrict__ W2,
                            const float* __restrict__ W3,
                            const float* __restrict__ Wo1, const float* __restrict__ Wo2,
                            const float* __restrict__ Wo3,
                            u16* __restrict__ tA, u16* __restrict__ WqkvT,
                            u16* __restrict__ WoT)
{
    int idx = blockIdx.x * blockDim.x + threadIdx.x;
    const int TA_N = 3 * N_TOK * KPAD;
    const int WQ_N = 3 * OUT3 * KPAD;
    const int WO_N = 3 * DIMF * RDIM;
    if (idx < TA_N) {
        int m = idx / (N_TOK * KPAD);
        int rem = idx - m * (N_TOK * KPAD);
        int row = rem / KPAD;
        int col = rem - row * KPAD;
        const float* t = (m == 0) ? t1 : (m == 1) ? t2 : t1c;
        tA[idx] = (col < DIMF) ? f2bf(t[row * DIMF + col]) : (u16)0;
    } else if (idx < TA_N + WQ_N) {
        int i = idx - TA_N;
        int m = i / (OUT3 * KPAD);
        int rem = i - m * (OUT3 * KPAD);
        int n = rem / KPAD;
        int c = rem - n * KPAD;
        const float* W = (m == 0) ? W1 : (m == 1) ? W2 : W3;
        WqkvT[i] = (c < DIMF) ? f2bf(W[c * OUT3 + n]) : (u16)0;
    } else if (idx < TA_N + WQ_N + WO_N) {
        int i = idx - TA_N - WQ_N;
        int m = i / (DIMF * RDIM);
        int rem = i - m * (DIMF * RDIM);
        int n = rem / RDIM;
        int c = rem - n * RDIM;
        const float* W = (m == 0) ? Wo1 : (m == 1) ? Wo2 : Wo3;
        WoT[i] = f2bf(W[c * DIMF + n]);
    }
}

// ---------------------------------------------------------------- QKV gemm
__global__ __launch_bounds__(256, 1) void qkv_gemm(
    const u16* __restrict__ tA, const u16* __restrict__ WqkvT,
    const float* __restrict__ b1, const float* __restrict__ b2, const float* __restrict__ b3,
    u16* __restrict__ qbuf, u16* __restrict__ kbuf, u16* __restrict__ vT)
{
    const int mt = blockIdx.x, nt = blockIdx.y, mod = blockIdx.z;
    const u16* A = tA + mod * (N_TOK * KPAD);
    const u16* B = WqkvT + mod * (OUT3 * KPAD);
    const float* bias = (mod == 0) ? b1 : (mod == 1) ? b2 : b3;

    __shared__ alignas(16) u16 Al[128 * 40];
    __shared__ alignas(16) u16 Bl[128 * 40];

    const int tid = threadIdx.x;
    const int lane = tid & 63;
    const int w = tid >> 6;
    const int wm = w & 1, wn = w >> 1;
    const int l31 = lane & 31, h = lane >> 5;

    f32x16 acc[2][2];
#pragma unroll
    for (int i = 0; i < 2; i++)
#pragma unroll
        for (int j = 0; j < 2; j++)
#pragma unroll
            for (int r = 0; r < 16; r++) acc[i][j][r] = 0.f;

    for (int kt = 0; kt < KPAD / 32; kt++) {
#pragma unroll
        for (int it = 0; it < 2; it++) {
            int idx = it * 256 + tid;
            int row = idx >> 2;
            int c8 = (idx & 3) * 8;
            uint4 va = *reinterpret_cast<const uint4*>(&A[(mt * 128 + row) * KPAD + kt * 32 + c8]);
            *reinterpret_cast<uint4*>(&Al[row * 40 + c8]) = va;
            uint4 vb = *reinterpret_cast<const uint4*>(&B[(nt * 128 + row) * KPAD + kt * 32 + c8]);
            *reinterpret_cast<uint4*>(&Bl[row * 40 + c8]) = vb;
        }
        __syncthreads();
#pragma unroll
        for (int kc = 0; kc < 2; kc++) {
            bf16x8 af[2], bfr[2];
#pragma unroll
            for (int mr = 0; mr < 2; mr++)
                af[mr] = ld_frag(&Al[(wm * 64 + mr * 32 + l31) * 40 + kc * 16 + h * 8]);
#pragma unroll
            for (int nr = 0; nr < 2; nr++)
                bfr[nr] = ld_frag(&Bl[(wn * 64 + nr * 32 + l31) * 40 + kc * 16 + h * 8]);
#pragma unroll
            for (int mr = 0; mr < 2; mr++)
#pragma unroll
                for (int nr = 0; nr < 2; nr++)
                    acc[mr][nr] = mfma_b(af[mr], bfr[nr], acc[mr][nr]);
        }
        __syncthreads();
    }

    u16* qb = qbuf + mod * (N_TOK * OUTD);
    u16* kb = kbuf + mod * (N_TOK * OUTD);
    u16* vb = vT + mod * (OUTD * N_TOK);
#pragma unroll
    for (int mr = 0; mr < 2; mr++)
#pragma unroll
        for (int nr = 0; nr < 2; nr++)
#pragma unroll
            for (int r = 0; r < 16; r++) {
                int row = mt * 128 + wm * 64 + mr * 32 + (r & 3) + 8 * (r >> 2) + 4 * h;
                int col = nt * 128 + wn * 64 + nr * 32 + l31;
                u16 bv = f2bf(acc[mr][nr][r] + bias[col]);
                int cs = col >> 8, cc = col & 255;
                if (cs == 0)      qb[row * OUTD + cc] = bv;
                else if (cs == 1) kb[row * OUTD + cc] = bv;
                else              vb[cc * N_TOK + row] = bv;   // v transposed
            }
}

// ---------------------------------------------------------------- attention
// Block: 256 thr = 4 waves sharing one staged K/V tile; each wave owns 32 of
// 128 q rows. S^T = K Q^T (C-layout col = q), P^T built in registers via
// half-wave shuffles, O^T = V^T P^T in regs. Split-K partials combined later.
__global__ __launch_bounds__(256, 4) void attn_kernel(
    const u16* __restrict__ qbuf, const u16* __restrict__ kbuf,
    const u16* __restrict__ vT, u16* __restrict__ Opart, float* __restrict__ lpart)
{
    const int qt = blockIdx.x;   // 0..31  (128-row q tile)
    const int g  = blockIdx.y;   // 0..5
    const int c  = blockIdx.z;   // 0..NCHUNK-1
    const int kv = g >> 1;
    const int mn = (kv == 0) ? 1 : 0;
    const int mx = (kv == 2) ? 1 : 2;
    const int qm = (g & 1) ? mx : mn;

    const u16* Qg = qbuf + qm * (N_TOK * OUTD);
    const u16* Kg = kbuf + kv * (N_TOK * OUTD);
    const u16* Vg = vT + kv * (OUTD * N_TOK);
    u16* Op = Opart + ((size_t)(c * 6 + g) * N_TOK + qt * 128) * OUTD;
    float* lp = lpart + (c * 6 + g) * N_TOK + qt * 128;

    __shared__ alignas(16) u16 Kl[32 * 264];
    __shared__ alignas(16) u16 Vl[256 * 40];

    const int tid = threadIdx.x;
    const int lane = tid & 63;
    const int w = tid >> 6;           // 0..3
    const int l31 = lane & 31, h = lane >> 5;
    const int q0 = qt * 128 + w * 32;

    bf16x8 qf[16];
#pragma unroll
    for (int dc = 0; dc < 16; dc++)
        qf[dc] = ld_frag(&Qg[(q0 + l31) * OUTD + dc * 16 + h * 8]);

    f32x16 Oacc[8];
#pragma unroll
    for (int nb = 0; nb < 8; nb++)
#pragma unroll
        for (int r = 0; r < 16; r++) Oacc[nb][r] = 0.f;
    float lsum = 0.f;

    const int k0base = c * (N_TOK / NCHUNK);
    for (int kt = 0; kt < (N_TOK / NCHUNK) / 32; kt++) {
        const int k0 = k0base + kt * 32;
        // stage K tile: 32 keys x 256 d  (1024 uint4 / 256 thr = 4 each)
#pragma unroll
        for (int it = 0; it < 4; it++) {
            int idx = it * 256 + tid;
            int row = idx >> 5;
            int c8 = (idx & 31) * 8;
            uint4 v = *reinterpret_cast<const uint4*>(&Kg[(k0 + row) * OUTD + c8]);
            *reinterpret_cast<uint4*>(&Kl[row * 264 + c8]) = v;
        }
        // stage V^T tile: 256 d x 32 keys
#pragma unroll
        for (int it = 0; it < 4; it++) {
            int idx = it * 256 + tid;
            int row = idx >> 2;
            int c8 = (idx & 3) * 8;
            uint4 v = *reinterpret_cast<const uint4*>(&Vg[row * N_TOK + k0 + c8]);
            *reinterpret_cast<uint4*>(&Vl[row * 40 + c8]) = v;
        }
        __syncthreads();

        // S^T[key][q] = K Q^T
        f32x16 S;
#pragma unroll
        for (int r = 0; r < 16; r++) S[r] = 0.f;
#pragma unroll
        for (int dc = 0; dc < 16; dc++) {
            bf16x8 kf = ld_frag(&Kl[l31 * 264 + dc * 16 + h * 8]);
            S = mfma_b(kf, qf[dc], S);
        }

        // P^T = exp(S^T - 16); per-lane partial of column sums
        float e[16];
#pragma unroll
        for (int r = 0; r < 16; r++) { e[r] = __expf(S[r] - SHIFT); lsum += e[r]; }
        u32 p[8];
#pragma unroll
        for (int i = 0; i < 8; i++)
            p[i] = (u32)f2bf(e[2 * i]) | ((u32)f2bf(e[2 * i + 1]) << 16);
        u32 x[8];
#pragma unroll
        for (int i = 0; i < 8; i++)
            x[i] = (u32)__shfl_xor((int)p[i], 32, 64);
        uint4 b0, b1;
        b0.x = h ? x[2] : p[0]; b0.y = h ? x[3] : p[1];
        b0.z = h ? p[2] : x[0]; b0.w = h ? p[3] : x[1];
        b1.x = h ? x[6] : p[4]; b1.y = h ? x[7] : p[5];
        b1.z = h ? p[6] : x[4]; b1.w = h ? p[7] : x[5];
        bf16x8 pb0 = __builtin_bit_cast(bf16x8, b0);
        bf16x8 pb1 = __builtin_bit_cast(bf16x8, b1);

        // O^T[d][q] += V^T[d][k] P^T[k][q]
#pragma unroll
        for (int nb = 0; nb < 8; nb++) {
            bf16x8 vf0 = ld_frag(&Vl[(nb * 32 + l31) * 40 + h * 8]);
            bf16x8 vf1 = ld_frag(&Vl[(nb * 32 + l31) * 40 + 16 + h * 8]);
            Oacc[nb] = mfma_b(vf0, pb0, Oacc[nb]);
            Oacc[nb] = mfma_b(vf1, pb1, Oacc[nb]);
        }
        __syncthreads();
    }

    // l partial: combine h-halves (column q = l31)
    lsum += __shfl_xor(lsum, 32, 64);
    if (lane < 32) lp[w * 32 + lane] = lsum;

    // transpose O^T -> [q][d] through wave-private LDS scratch, store bf16
    // (after final __syncthreads all waves are done reading Kl/Vl)
    float* Tb = reinterpret_cast<float*>(Kl) + w * (32 * 33);
#pragma unroll
    for (int nb = 0; nb < 8; nb++) {
#pragma unroll
        for (int r = 0; r < 16; r++)
            Tb[((r & 3) + 8 * (r >> 2) + 4 * h) * 33 + l31] = Oacc[nb][r];
        __builtin_amdgcn_s_waitcnt(0);  // lgkm drain before re-read (wave-private)
#pragma unroll
        for (int qq = 0; qq < 16; qq++) {
            float v = Tb[l31 * 33 + qq * 2 + h];
            Op[(w * 32 + qq * 2 + h) * OUTD + nb * 32 + l31] = f2bf(v);
        }
        __builtin_amdgcn_s_waitcnt(0);
    }
}

// ---------------------------------------------------------------- combine
__global__ __launch_bounds__(256, 1) void combine_kernel(
    const u16* __restrict__ Opart, const float* __restrict__ lpart,
    const u16* __restrict__ kbuf, u16* __restrict__ rbuf)
{
    const int q = blockIdx.x;
    const int g = blockIdx.y;
    const int d = threadIdx.x;
    const int kv = g >> 1;
    const int mn = (kv == 0) ? 1 : 0;
    const int mx = (kv == 2) ? 1 : 2;
    const int qm = (g & 1) ? mx : mn;
    const int sm = (qm == 0) ? 1 : 0;
    const int slot = (kv == sm) ? 0 : 1;

    float o = 0.f, l = 0.f;
#pragma unroll
    for (int c = 0; c < NCHUNK; c++) {
        o += bf2f(Opart[((size_t)(c * 6 + g) * N_TOK + q) * OUTD + d]);
        l += lpart[(c * 6 + g) * N_TOK + q];
    }
    float res = o / l + bf2f(kbuf[qm * (N_TOK * OUTD) + q * OUTD + d]);
    rbuf[qm * (size_t)(N_TOK * RDIM) + q * RDIM + slot * OUTD + d] = f2bf(res);
}

// ---------------------------------------------------------------- out proj
__global__ __launch_bounds__(256, 1) void proj_gemm(
    const u16* __restrict__ rbuf, const u16* __restrict__ WoT,
    const float* __restrict__ bo1, const float* __restrict__ bo2, const float* __restrict__ bo3,
    const float* __restrict__ t1, const float* __restrict__ t2, const float* __restrict__ t1c,
    float* __restrict__ feat)
{
    const int mt = blockIdx.x, nt = blockIdx.y, mod = blockIdx.z;
    const u16* A = rbuf + mod * (N_TOK * RDIM);
    const u16* B = WoT + mod * (DIMF * RDIM);
    const float* bias = (mod == 0) ? bo1 : (mod == 1) ? bo2 : bo3;
    const float* tres = (mod == 0) ? t1 : (mod == 1) ? t2 : t1c;

    __shared__ alignas(16) u16 Al[128 * 40];
    __shared__ alignas(16) u16 Bl[128 * 40];

    const int tid = threadIdx.x;
    const int lane = tid & 63;
    const int w = tid >> 6;
    const int wm = w & 1, wn = w >> 1;
    const int l31 = lane & 31, h = lane >> 5;

    f32x16 acc[2][2];
#pragma unroll
    for (int i = 0; i < 2; i++)
#pragma unroll
        for (int j = 0; j < 2; j++)
#pragma unroll
            for (int r = 0; r < 16; r++) acc[i][j][r] = 0.f;

    for (int kt = 0; kt < RDIM / 32; kt++) {
#pragma unroll
        for (int it = 0; it < 2; it++) {
            int idx = it * 256 + tid;
            int row = idx >> 2;
            int c8 = (idx & 3) * 8;
            uint4 va = *reinterpret_cast<const uint4*>(&A[(mt * 128 + row) * RDIM + kt * 32 + c8]);
            *reinterpret_cast<uint4*>(&Al[row * 40 + c8]) = va;
            int n = nt * 128 + row;
            uint4 vb;
            if (n < DIMF) vb = *reinterpret_cast<const uint4*>(&B[n * RDIM + kt * 32 + c8]);
            else { vb.x = vb.y = vb.z = vb.w = 0u; }
            *reinterpret_cast<uint4*>(&Bl[row * 40 + c8]) = vb;
        }
        __syncthreads();
#pragma unroll
        for (int kc = 0; kc < 2; kc++) {
            bf16x8 af[2], bfr[2];
#pragma unroll
            for (int mr = 0; mr < 2; mr++)
                af[mr] = ld_frag(&Al[(wm * 64 + mr * 32 + l31) * 40 + kc * 16 + h * 8]);
#pragma unroll
            for (int nr = 0; nr < 2; nr++)
                bfr[nr] = ld_frag(&Bl[(wn * 64 + nr * 32 + l31) * 40 + kc * 16 + h * 8]);
#pragma unroll
            for (int mr = 0; mr < 2; mr++)
#pragma unroll
                for (int nr = 0; nr < 2; nr++)
                    acc[mr][nr] = mfma_b(af[mr], bfr[nr], acc[mr][nr]);
        }
        __syncthreads();
    }

#pragma unroll
    for (int mr = 0; mr < 2; mr++)
#pragma unroll
        for (int nr = 0; nr < 2; nr++)
#pragma unroll
            for (int r = 0; r < 16; r++) {
                int row = mt * 128 + wm * 64 + mr * 32 + (r & 3) + 8 * (r >> 2) + 4 * h;
                int col = nt * 128 + wn * 64 + nr * 32 + l31;
                if (col < DIMF) {
                    float v = acc[mr][nr][r] + bias[col] + tres[row * DIMF + col];
                    feat[row * FDIM + mod * DIMF + col] = v;
                }
            }
}

// ---------------------------------------------------------------- LN + head
__global__ __launch_bounds__(256, 1) void ln_head(
    const float* __restrict__ feat, const float* __restrict__ gam,
    const float* __restrict__ bet, const float* __restrict__ Wh,
    const float* __restrict__ bh, float* __restrict__ out)
{
    const int row = blockIdx.x;
    const float* x = feat + row * FDIM;
    const int tid = threadIdx.x;
    float v[7];
    float s = 0.f, ss = 0.f;
#pragma unroll
    for (int i = 0; i < 7; i++) {
        int idx = tid + i * 256;
        float val = (idx < FDIM) ? x[idx] : 0.f;
        v[i] = val; s += val; ss += val * val;
    }
#pragma unroll
    for (int m = 1; m < 64; m <<= 1) { s += __shfl_xor(s, m, 64); ss += __shfl_xor(ss, m, 64); }
    __shared__ float red[8];
    const int w = tid >> 6, lane = tid & 63;
    if (lane == 0) { red[w] = s; red[4 + w] = ss; }
    __syncthreads();
    s = red[0] + red[1] + red[2] + red[3];
    ss = red[4] + red[5] + red[6] + red[7];
    const float mu = s / (float)FDIM;
    const float var = ss / (float)FDIM - mu * mu;
    const float rstd = rsqrtf(var + 1e-5f);
    float a0 = 0.f, a1 = 0.f;
#pragma unroll
    for (int i = 0; i < 7; i++) {
        int idx = tid + i * 256;
        if (idx < FDIM) {
            float nv = (v[i] - mu) * rstd * gam[idx] + bet[idx];
            a0 += nv * Wh[idx * 2];
            a1 += nv * Wh[idx * 2 + 1];
        }
    }
#pragma unroll
    for (int m = 1; m < 64; m <<= 1) { a0 += __shfl_xor(a0, m, 64); a1 += __shfl_xor(a1, m, 64); }
    __shared__ float red2[8];
    if (lane == 0) { red2[w] = a0; red2[4 + w] = a1; }
    __syncthreads();
    if (tid == 0) {
        out[row * 2 + 0] = red2[0] + red2[1] + red2[2] + red2[3] + bh[0];
        out[row * 2 + 1] = red2[4] + red2[5] + red2[6] + red2[7] + bh[1];
    }
}

// ---------------------------------------------------------------- launch
extern "C" void kernel_launch(void* const* d_in, const int* in_sizes, int n_in,
                              void* d_out, int out_size, void* d_ws, size_t ws_size,
                              hipStream_t stream)
{
    const float* t1    = (const float*)d_in[0];
    const float* t2    = (const float*)d_in[1];
    const float* t1c   = (const float*)d_in[2];
    const float* Wqkv1 = (const float*)d_in[3];
    const float* bqkv1 = (const float*)d_in[4];
    const float* Wqkv2 = (const float*)d_in[5];
    const float* bqkv2 = (const float*)d_in[6];
    const float* Wqkv3 = (const float*)d_in[7];
    const float* bqkv3 = (const float*)d_in[8];
    const float* Wo1   = (const float*)d_in[9];
    const float* bo1   = (const float*)d_in[10];
    const float* Wo2   = (const float*)d_in[11];
    const float* bo2   = (const float*)d_in[12];
    const float* Wo3   = (const float*)d_in[13];
    const float* bo3   = (const float*)d_in[14];
    const float* ln_g  = (const float*)d_in[15];
    const float* ln_b  = (const float*)d_in[16];
    const float* Wh    = (const float*)d_in[17];
    const float* bh    = (const float*)d_in[18];

    char* ws = (char*)d_ws;
    size_t off = 0;
    u16* tA    = (u16*)(ws + off); off += (size_t)3 * N_TOK * KPAD * 2;
    u16* WqkvT = (u16*)(ws + off); off += (size_t)3 * OUT3 * KPAD * 2;
    u16* WoT   = (u16*)(ws + off); off += (size_t)3 * DIMF * RDIM * 2;
    u16* qbuf  = (u16*)(ws + off); off += (size_t)3 * N_TOK * OUTD * 2;
    u16* kbuf  = (u16*)(ws + off); off += (size_t)3 * N_TOK * OUTD * 2;
    u16* vT    = (u16*)(ws + off); off += (size_t)3 * OUTD * N_TOK * 2;
    u16* rbuf  = (u16*)(ws + off); off += (size_t)3 * N_TOK * RDIM * 2;
    u16* Opart = (u16*)(ws + off); off += (size_t)NCHUNK * 6 * N_TOK * OUTD * 2;
    float* lpart = (float*)(ws + off); off += (size_t)NCHUNK * 6 * N_TOK * 4;

    float* out  = (float*)d_out;
    float* feat = out + N_TOK * 2;

    const int prep_total = 3 * N_TOK * KPAD + 3 * OUT3 * KPAD + 3 * DIMF * RDIM;
    prep_kernel<<<(prep_total + 255) / 256, 256, 0, stream>>>(
        t1, t2, t1c, Wqkv1, Wqkv2, Wqkv3, Wo1, Wo2, Wo3, tA, WqkvT, WoT);

    qkv_gemm<<<dim3(32, 6, 3), 256, 0, stream>>>(
        tA, WqkvT, bqkv1, bqkv2, bqkv3, qbuf, kbuf, vT);

    attn_kernel<<<dim3(32, 6, NCHUNK), 256, 0, stream>>>(qbuf, kbuf, vT, Opart, lpart);

    combine_kernel<<<dim3(N_TOK, 6), 256, 0, stream>>>(Opart, lpart, kbuf, rbuf);

    proj_gemm<<<dim3(32, 5, 3), 256, 0, stream>>>(
        rbuf, WoT, bo1, bo2, bo3, t1, t2, t1c, feat);

    ln_head<<<4096, 256, 0, stream>>>(feat, ln_g, ln_b, Wh, bh, out);
}

// Round 4
// 548.847 us; speedup vs baseline: 2.1167x; 2.1167x over previous
//
#include <hip/hip_runtime.h>
#include <hip/hip_bf16.h>

typedef unsigned short u16;
typedef unsigned int u32;
typedef __attribute__((ext_vector_type(8))) __bf16 bf16x8;
typedef __attribute__((ext_vector_type(16))) float f32x16;

#define N_TOK 4096
#define DIMF  514
#define KPAD  544      // 17*32, zero-padded K for QKV gemm
#define OUT3  768
#define OUTD  256
#define RDIM  512
#define FDIM  1542
#define SHIFT 16.0f
#define NCHUNK 4       // split-K chunks over the 4096 keys

__device__ __forceinline__ bf16x8 ld_frag(const u16* p) {
    return __builtin_bit_cast(bf16x8, *reinterpret_cast<const uint4*>(p));
}
__device__ __forceinline__ u16 f2bf(float x) {
    return __builtin_bit_cast(u16, __float2bfloat16(x));
}
__device__ __forceinline__ float bf2f(u16 u) {
    return __bfloat162float(__builtin_bit_cast(__hip_bfloat16, u));
}
__device__ __forceinline__ f32x16 mfma_b(bf16x8 a, bf16x8 b, f32x16 c) {
    return __builtin_amdgcn_mfma_f32_32x32x16_bf16(a, b, c, 0, 0, 0);
}

// ---------------------------------------------------------------- prep
__global__ void prep_kernel(const float* __restrict__ t1, const float* __restrict__ t2,
                            const float* __restrict__ t1c,
                            const float* __restrict__ W1, const float* __restrict__ W2,
                            const float* __restrict__ W3,
                            const float* __restrict__ Wo1, const float* __restrict__ Wo2,
                            const float* __restrict__ Wo3,
                            u16* __restrict__ tA, u16* __restrict__ WqkvT,
                            u16* __restrict__ WoT)
{
    int idx = blockIdx.x * blockDim.x + threadIdx.x;
    const int TA_N = 3 * N_TOK * KPAD;
    const int WQ_N = 3 * OUT3 * KPAD;
    const int WO_N = 3 * DIMF * RDIM;
    if (idx < TA_N) {
        int m = idx / (N_TOK * KPAD);
        int rem = idx - m * (N_TOK * KPAD);
        int row = rem / KPAD;
        int col = rem - row * KPAD;
        const float* t = (m == 0) ? t1 : (m == 1) ? t2 : t1c;
        tA[idx] = (col < DIMF) ? f2bf(t[row * DIMF + col]) : (u16)0;
    } else if (idx < TA_N + WQ_N) {
        int i = idx - TA_N;
        int m = i / (OUT3 * KPAD);
        int rem = i - m * (OUT3 * KPAD);
        int n = rem / KPAD;
        int c = rem - n * KPAD;
        const float* W = (m == 0) ? W1 : (m == 1) ? W2 : W3;
        WqkvT[i] = (c < DIMF) ? f2bf(W[c * OUT3 + n]) : (u16)0;
    } else if (idx < TA_N + WQ_N + WO_N) {
        int i = idx - TA_N - WQ_N;
        int m = i / (DIMF * RDIM);
        int rem = i - m * (DIMF * RDIM);
        int n = rem / RDIM;
        int c = rem - n * RDIM;
        const float* W = (m == 0) ? Wo1 : (m == 1) ? Wo2 : Wo3;
        WoT[i] = f2bf(W[c * DIMF + n]);
    }
}

// ---------------------------------------------------------------- QKV gemm
__global__ __launch_bounds__(256, 1) void qkv_gemm(
    const u16* __restrict__ tA, const u16* __restrict__ WqkvT,
    const float* __restrict__ b1, const float* __restrict__ b2, const float* __restrict__ b3,
    u16* __restrict__ qbuf, u16* __restrict__ kbuf, u16* __restrict__ vT)
{
    const int mt = blockIdx.x, nt = blockIdx.y, mod = blockIdx.z;
    const u16* A = tA + mod * (N_TOK * KPAD);
    const u16* B = WqkvT + mod * (OUT3 * KPAD);
    const float* bias = (mod == 0) ? b1 : (mod == 1) ? b2 : b3;

    __shared__ alignas(16) u16 Al[128 * 40];
    __shared__ alignas(16) u16 Bl[128 * 40];

    const int tid = threadIdx.x;
    const int lane = tid & 63;
    const int w = tid >> 6;
    const int wm = w & 1, wn = w >> 1;
    const int l31 = lane & 31, h = lane >> 5;

    f32x16 acc[2][2];
#pragma unroll
    for (int i = 0; i < 2; i++)
#pragma unroll
        for (int j = 0; j < 2; j++)
#pragma unroll
            for (int r = 0; r < 16; r++) acc[i][j][r] = 0.f;

    for (int kt = 0; kt < KPAD / 32; kt++) {
#pragma unroll
        for (int it = 0; it < 2; it++) {
            int idx = it * 256 + tid;
            int row = idx >> 2;
            int c8 = (idx & 3) * 8;
            uint4 va = *reinterpret_cast<const uint4*>(&A[(mt * 128 + row) * KPAD + kt * 32 + c8]);
            *reinterpret_cast<uint4*>(&Al[row * 40 + c8]) = va;
            uint4 vb = *reinterpret_cast<const uint4*>(&B[(nt * 128 + row) * KPAD + kt * 32 + c8]);
            *reinterpret_cast<uint4*>(&Bl[row * 40 + c8]) = vb;
        }
        __syncthreads();
#pragma unroll
        for (int kc = 0; kc < 2; kc++) {
            bf16x8 af[2], bfr[2];
#pragma unroll
            for (int mr = 0; mr < 2; mr++)
                af[mr] = ld_frag(&Al[(wm * 64 + mr * 32 + l31) * 40 + kc * 16 + h * 8]);
#pragma unroll
            for (int nr = 0; nr < 2; nr++)
                bfr[nr] = ld_frag(&Bl[(wn * 64 + nr * 32 + l31) * 40 + kc * 16 + h * 8]);
#pragma unroll
            for (int mr = 0; mr < 2; mr++)
#pragma unroll
                for (int nr = 0; nr < 2; nr++)
                    acc[mr][nr] = mfma_b(af[mr], bfr[nr], acc[mr][nr]);
        }
        __syncthreads();
    }

    u16* qb = qbuf + mod * (N_TOK * OUTD);
    u16* kb = kbuf + mod * (N_TOK * OUTD);
    u16* vb = vT + mod * (OUTD * N_TOK);
#pragma unroll
    for (int mr = 0; mr < 2; mr++)
#pragma unroll
        for (int nr = 0; nr < 2; nr++)
#pragma unroll
            for (int r = 0; r < 16; r++) {
                int row = mt * 128 + wm * 64 + mr * 32 + (r & 3) + 8 * (r >> 2) + 4 * h;
                int col = nt * 128 + wn * 64 + nr * 32 + l31;
                u16 bv = f2bf(acc[mr][nr][r] + bias[col]);
                int cs = col >> 8, cc = col & 255;
                if (cs == 0)      qb[row * OUTD + cc] = bv;
                else if (cs == 1) kb[row * OUTD + cc] = bv;
                else              vb[cc * N_TOK + row] = bv;   // v transposed
            }
}

// ---------------------------------------------------------------- attention
// Block: 64 Q rows (2 waves x 32 q), one key chunk of 1024 keys in 32-key tiles.
// S^T = K Q^T (C-layout col = q), P^T built in registers via half-wave shuffles,
// O^T = V^T P^T accumulated in regs. Partials (O, l) summed by combine kernel.
// VGPR budget note: needs ~256 regs/wave (qf 64 + Oacc 128 + temps) ->
// __launch_bounds__(128,2); do NOT raise min-waves (R3: 4 -> spill -> 4.5 GB scratch).
__global__ __launch_bounds__(128, 2) void attn_kernel(
    const u16* __restrict__ qbuf, const u16* __restrict__ kbuf,
    const u16* __restrict__ vT, u16* __restrict__ Opart, float* __restrict__ lpart)
{
    const int qt = blockIdx.x;   // 0..63  (64-row q tile)
    const int g  = blockIdx.y;   // 0..5
    const int c  = blockIdx.z;   // 0..NCHUNK-1
    const int kv = g >> 1;
    const int mn = (kv == 0) ? 1 : 0;
    const int mx = (kv == 2) ? 1 : 2;
    const int qm = (g & 1) ? mx : mn;

    const u16* Qg = qbuf + qm * (N_TOK * OUTD);
    const u16* Kg = kbuf + kv * (N_TOK * OUTD);
    const u16* Vg = vT + kv * (OUTD * N_TOK);
    u16* Op = Opart + ((size_t)(c * 6 + g) * N_TOK + qt * 64) * OUTD;
    float* lp = lpart + (c * 6 + g) * N_TOK + qt * 64;

    __shared__ alignas(16) u16 Kl[32 * 264];
    __shared__ alignas(16) u16 Vl[256 * 40];

    const int tid = threadIdx.x;
    const int lane = tid & 63;
    const int w = tid >> 6;
    const int l31 = lane & 31, h = lane >> 5;
    const int q0 = qt * 64 + w * 32;

    bf16x8 qf[16];
#pragma unroll
    for (int dc = 0; dc < 16; dc++)
        qf[dc] = ld_frag(&Qg[(q0 + l31) * OUTD + dc * 16 + h * 8]);

    f32x16 Oacc[8];
#pragma unroll
    for (int nb = 0; nb < 8; nb++)
#pragma unroll
        for (int r = 0; r < 16; r++) Oacc[nb][r] = 0.f;
    float lsum = 0.f;

    const int k0base = c * (N_TOK / NCHUNK);
    for (int kt = 0; kt < (N_TOK / NCHUNK) / 32; kt++) {
        const int k0 = k0base + kt * 32;
        // stage K tile: 32 keys x 256 d  (1024 uint4 chunks / 128 thr = 8 each)
#pragma unroll
        for (int it = 0; it < 8; it++) {
            int idx = it * 128 + tid;
            int row = idx >> 5;
            int c8 = (idx & 31) * 8;
            uint4 v = *reinterpret_cast<const uint4*>(&Kg[(k0 + row) * OUTD + c8]);
            *reinterpret_cast<uint4*>(&Kl[row * 264 + c8]) = v;
        }
        // stage V^T tile: 256 d x 32 keys
#pragma unroll
        for (int it = 0; it < 8; it++) {
            int idx = it * 128 + tid;
            int row = idx >> 2;
            int c8 = (idx & 3) * 8;
            uint4 v = *reinterpret_cast<const uint4*>(&Vg[row * N_TOK + k0 + c8]);
            *reinterpret_cast<uint4*>(&Vl[row * 40 + c8]) = v;
        }
        __syncthreads();

        // S^T[key][q] = K Q^T
        f32x16 S;
#pragma unroll
        for (int r = 0; r < 16; r++) S[r] = 0.f;
#pragma unroll
        for (int dc = 0; dc < 16; dc++) {
            bf16x8 kf = ld_frag(&Kl[l31 * 264 + dc * 16 + h * 8]);
            S = mfma_b(kf, qf[dc], S);
        }

        // P^T = exp(S^T - 16); row sums accumulate per-lane
        float e[16];
#pragma unroll
        for (int r = 0; r < 16; r++) { e[r] = __expf(S[r] - SHIFT); lsum += e[r]; }
        u32 p[8];
#pragma unroll
        for (int i = 0; i < 8; i++)
            p[i] = (u32)f2bf(e[2 * i]) | ((u32)f2bf(e[2 * i + 1]) << 16);
        u32 x[8];
#pragma unroll
        for (int i = 0; i < 8; i++)
            x[i] = (u32)__shfl_xor((int)p[i], 32, 64);
        uint4 b0, b1;
        b0.x = h ? x[2] : p[0]; b0.y = h ? x[3] : p[1];
        b0.z = h ? p[2] : x[0]; b0.w = h ? p[3] : x[1];
        b1.x = h ? x[6] : p[4]; b1.y = h ? x[7] : p[5];
        b1.z = h ? p[6] : x[4]; b1.w = h ? p[7] : x[5];
        bf16x8 pb0 = __builtin_bit_cast(bf16x8, b0);
        bf16x8 pb1 = __builtin_bit_cast(bf16x8, b1);

        // O^T[d][q] += V^T[d][k] P^T[k][q]
#pragma unroll
        for (int nb = 0; nb < 8; nb++) {
            bf16x8 vf0 = ld_frag(&Vl[(nb * 32 + l31) * 40 + h * 8]);
            bf16x8 vf1 = ld_frag(&Vl[(nb * 32 + l31) * 40 + 16 + h * 8]);
            Oacc[nb] = mfma_b(vf0, pb0, Oacc[nb]);
            Oacc[nb] = mfma_b(vf1, pb1, Oacc[nb]);
        }
        __syncthreads();
    }

    // l partial: combine h-halves (column q = l31)
    lsum += __shfl_xor(lsum, 32, 64);
    if (lane < 32) lp[w * 32 + lane] = lsum;

    // transpose O^T -> [q][d] through wave-private LDS scratch, store bf16
    float* Tb = (w == 0) ? reinterpret_cast<float*>(Kl) : reinterpret_cast<float*>(Vl);
#pragma unroll
    for (int nb = 0; nb < 8; nb++) {
#pragma unroll
        for (int r = 0; r < 16; r++)
            Tb[((r & 3) + 8 * (r >> 2) + 4 * h) * 33 + l31] = Oacc[nb][r];
        __builtin_amdgcn_s_waitcnt(0);  // lgkm drain before re-read (wave-private)
#pragma unroll
        for (int qq = 0; qq < 16; qq++) {
            float v = Tb[l31 * 33 + qq * 2 + h];
            Op[(w * 32 + qq * 2 + h) * OUTD + nb * 32 + l31] = f2bf(v);
        }
        __builtin_amdgcn_s_waitcnt(0);
    }
}

// ---------------------------------------------------------------- combine
// out_partials: o = sum(O_c)/sum(l_c) + k_residual -> rbuf bf16 [qm][q][slot*256+d]
__global__ __launch_bounds__(256, 1) void combine_kernel(
    const u16* __restrict__ Opart, const float* __restrict__ lpart,
    const u16* __restrict__ kbuf, u16* __restrict__ rbuf)
{
    const int q = blockIdx.x;
    const int g = blockIdx.y;
    const int d = threadIdx.x;
    const int kv = g >> 1;
    const int mn = (kv == 0) ? 1 : 0;
    const int mx = (kv == 2) ? 1 : 2;
    const int qm = (g & 1) ? mx : mn;
    const int sm = (qm == 0) ? 1 : 0;
    const int slot = (kv == sm) ? 0 : 1;

    float o = 0.f, l = 0.f;
#pragma unroll
    for (int c = 0; c < NCHUNK; c++) {
        o += bf2f(Opart[((size_t)(c * 6 + g) * N_TOK + q) * OUTD + d]);
        l += lpart[(c * 6 + g) * N_TOK + q];
    }
    float res = o / l + bf2f(kbuf[qm * (N_TOK * OUTD) + q * OUTD + d]);
    rbuf[qm * (size_t)(N_TOK * RDIM) + q * RDIM + slot * OUTD + d] = f2bf(res);
}

// ---------------------------------------------------------------- out proj
__global__ __launch_bounds__(256, 1) void proj_gemm(
    const u16* __restrict__ rbuf, const u16* __restrict__ WoT,
    const float* __restrict__ bo1, const float* __restrict__ bo2, const float* __restrict__ bo3,
    const float* __restrict__ t1, const float* __restrict__ t2, const float* __restrict__ t1c,
    float* __restrict__ feat)
{
    const int mt = blockIdx.x, nt = blockIdx.y, mod = blockIdx.z;
    const u16* A = rbuf + mod * (N_TOK * RDIM);
    const u16* B = WoT + mod * (DIMF * RDIM);
    const float* bias = (mod == 0) ? bo1 : (mod == 1) ? bo2 : bo3;
    const float* tres = (mod == 0) ? t1 : (mod == 1) ? t2 : t1c;

    __shared__ alignas(16) u16 Al[128 * 40];
    __shared__ alignas(16) u16 Bl[128 * 40];

    const int tid = threadIdx.x;
    const int lane = tid & 63;
    const int w = tid >> 6;
    const int wm = w & 1, wn = w >> 1;
    const int l31 = lane & 31, h = lane >> 5;

    f32x16 acc[2][2];
#pragma unroll
    for (int i = 0; i < 2; i++)
#pragma unroll
        for (int j = 0; j < 2; j++)
#pragma unroll
            for (int r = 0; r < 16; r++) acc[i][j][r] = 0.f;

    for (int kt = 0; kt < RDIM / 32; kt++) {
#pragma unroll
        for (int it = 0; it < 2; it++) {
            int idx = it * 256 + tid;
            int row = idx >> 2;
            int c8 = (idx & 3) * 8;
            uint4 va = *reinterpret_cast<const uint4*>(&A[(mt * 128 + row) * RDIM + kt * 32 + c8]);
            *reinterpret_cast<uint4*>(&Al[row * 40 + c8]) = va;
            int n = nt * 128 + row;
            uint4 vb;
            if (n < DIMF) vb = *reinterpret_cast<const uint4*>(&B[n * RDIM + kt * 32 + c8]);
            else { vb.x = vb.y = vb.z = vb.w = 0u; }
            *reinterpret_cast<uint4*>(&Bl[row * 40 + c8]) = vb;
        }
        __syncthreads();
#pragma unroll
        for (int kc = 0; kc < 2; kc++) {
            bf16x8 af[2], bfr[2];
#pragma unroll
            for (int mr = 0; mr < 2; mr++)
                af[mr] = ld_frag(&Al[(wm * 64 + mr * 32 + l31) * 40 + kc * 16 + h * 8]);
#pragma unroll
            for (int nr = 0; nr < 2; nr++)
                bfr[nr] = ld_frag(&Bl[(wn * 64 + nr * 32 + l31) * 40 + kc * 16 + h * 8]);
#pragma unroll
            for (int mr = 0; mr < 2; mr++)
#pragma unroll
                for (int nr = 0; nr < 2; nr++)
                    acc[mr][nr] = mfma_b(af[mr], bfr[nr], acc[mr][nr]);
        }
        __syncthreads();
    }

#pragma unroll
    for (int mr = 0; mr < 2; mr++)
#pragma unroll
        for (int nr = 0; nr < 2; nr++)
#pragma unroll
            for (int r = 0; r < 16; r++) {
                int row = mt * 128 + wm * 64 + mr * 32 + (r & 3) + 8 * (r >> 2) + 4 * h;
                int col = nt * 128 + wn * 64 + nr * 32 + l31;
                if (col < DIMF) {
                    float v = acc[mr][nr][r] + bias[col] + tres[row * DIMF + col];
                    feat[row * FDIM + mod * DIMF + col] = v;
                }
            }
}

// ---------------------------------------------------------------- LN + head
__global__ __launch_bounds__(256, 1) void ln_head(
    const float* __restrict__ feat, const float* __restrict__ gam,
    const float* __restrict__ bet, const float* __restrict__ Wh,
    const float* __restrict__ bh, float* __restrict__ out)
{
    const int row = blockIdx.x;
    const float* x = feat + row * FDIM;
    const int tid = threadIdx.x;
    float v[7];
    float s = 0.f, ss = 0.f;
#pragma unroll
    for (int i = 0; i < 7; i++) {
        int idx = tid + i * 256;
        float val = (idx < FDIM) ? x[idx] : 0.f;
        v[i] = val; s += val; ss += val * val;
    }
#pragma unroll
    for (int m = 1; m < 64; m <<= 1) { s += __shfl_xor(s, m, 64); ss += __shfl_xor(ss, m, 64); }
    __shared__ float red[8];
    const int w = tid >> 6, lane = tid & 63;
    if (lane == 0) { red[w] = s; red[4 + w] = ss; }
    __syncthreads();
    s = red[0] + red[1] + red[2] + red[3];
    ss = red[4] + red[5] + red[6] + red[7];
    const float mu = s / (float)FDIM;
    const float var = ss / (float)FDIM - mu * mu;
    const float rstd = rsqrtf(var + 1e-5f);
    float a0 = 0.f, a1 = 0.f;
#pragma unroll
    for (int i = 0; i < 7; i++) {
        int idx = tid + i * 256;
        if (idx < FDIM) {
            float nv = (v[i] - mu) * rstd * gam[idx] + bet[idx];
            a0 += nv * Wh[idx * 2];
            a1 += nv * Wh[idx * 2 + 1];
        }
    }
#pragma unroll
    for (int m = 1; m < 64; m <<= 1) { a0 += __shfl_xor(a0, m, 64); a1 += __shfl_xor(a1, m, 64); }
    __shared__ float red2[8];
    if (lane == 0) { red2[w] = a0; red2[4 + w] = a1; }
    __syncthreads();
    if (tid == 0) {
        out[row * 2 + 0] = red2[0] + red2[1] + red2[2] + red2[3] + bh[0];
        out[row * 2 + 1] = red2[4] + red2[5] + red2[6] + red2[7] + bh[1];
    }
}

// ---------------------------------------------------------------- launch
extern "C" void kernel_launch(void* const* d_in, const int* in_sizes, int n_in,
                              void* d_out, int out_size, void* d_ws, size_t ws_size,
                              hipStream_t stream)
{
    const float* t1    = (const float*)d_in[0];
    const float* t2    = (const float*)d_in[1];
    const float* t1c   = (const float*)d_in[2];
    const float* Wqkv1 = (const float*)d_in[3];
    const float* bqkv1 = (const float*)d_in[4];
    const float* Wqkv2 = (const float*)d_in[5];
    const float* bqkv2 = (const float*)d_in[6];
    const float* Wqkv3 = (const float*)d_in[7];
    const float* bqkv3 = (const float*)d_in[8];
    const float* Wo1   = (const float*)d_in[9];
    const float* bo1   = (const float*)d_in[10];
    const float* Wo2   = (const float*)d_in[11];
    const float* bo2   = (const float*)d_in[12];
    const float* Wo3   = (const float*)d_in[13];
    const float* bo3   = (const float*)d_in[14];
    const float* ln_g  = (const float*)d_in[15];
    const float* ln_b  = (const float*)d_in[16];
    const float* Wh    = (const float*)d_in[17];
    const float* bh    = (const float*)d_in[18];

    char* ws = (char*)d_ws;
    size_t off = 0;
    u16* tA    = (u16*)(ws + off); off += (size_t)3 * N_TOK * KPAD * 2;
    u16* WqkvT = (u16*)(ws + off); off += (size_t)3 * OUT3 * KPAD * 2;
    u16* WoT   = (u16*)(ws + off); off += (size_t)3 * DIMF * RDIM * 2;
    u16* qbuf  = (u16*)(ws + off); off += (size_t)3 * N_TOK * OUTD * 2;
    u16* kbuf  = (u16*)(ws + off); off += (size_t)3 * N_TOK * OUTD * 2;
    u16* vT    = (u16*)(ws + off); off += (size_t)3 * OUTD * N_TOK * 2;
    u16* rbuf  = (u16*)(ws + off); off += (size_t)3 * N_TOK * RDIM * 2;
    u16* Opart = (u16*)(ws + off); off += (size_t)NCHUNK * 6 * N_TOK * OUTD * 2;
    float* lpart = (float*)(ws + off); off += (size_t)NCHUNK * 6 * N_TOK * 4;

    float* out  = (float*)d_out;
    float* feat = out + N_TOK * 2;

    const int prep_total = 3 * N_TOK * KPAD + 3 * OUT3 * KPAD + 3 * DIMF * RDIM;
    prep_kernel<<<(prep_total + 255) / 256, 256, 0, stream>>>(
        t1, t2, t1c, Wqkv1, Wqkv2, Wqkv3, Wo1, Wo2, Wo3, tA, WqkvT, WoT);

    qkv_gemm<<<dim3(32, 6, 3), 256, 0, stream>>>(
        tA, WqkvT, bqkv1, bqkv2, bqkv3, qbuf, kbuf, vT);

    attn_kernel<<<dim3(64, 6, NCHUNK), 128, 0, stream>>>(qbuf, kbuf, vT, Opart, lpart);

    combine_kernel<<<dim3(N_TOK, 6), 256, 0, stream>>>(Opart, lpart, kbuf, rbuf);

    proj_gemm<<<dim3(32, 5, 3), 256, 0, stream>>>(
        rbuf, WoT, bo1, bo2, bo3, t1, t2, t1c, feat);

    ln_head<<<4096, 256, 0, stream>>>(feat, ln_g, ln_b, Wh, bh, out);
}

// Round 5
// 335.791 us; speedup vs baseline: 3.4598x; 1.6345x over previous
//
#include <hip/hip_runtime.h>
#include <hip/hip_bf16.h>

typedef unsigned short u16;
typedef unsigned int u32;
typedef __attribute__((ext_vector_type(8))) __bf16 bf16x8;
typedef __attribute__((ext_vector_type(16))) float f32x16;

#define N_TOK 4096
#define DIMF  514
#define KPAD  544      // 17*32, zero-padded K for QKV gemm
#define OUT3  768
#define OUTD  256
#define RDIM  512
#define FDIM  1542
#define SHIFT 16.0f
#define NCHUNK 4       // split-K chunks over the 4096 keys
#define KTILES ((N_TOK / NCHUNK) / 32)   // 32-key tiles per chunk

__device__ __forceinline__ bf16x8 ld_frag(const u16* p) {
    return __builtin_bit_cast(bf16x8, *reinterpret_cast<const uint4*>(p));
}
__device__ __forceinline__ u16 f2bf(float x) {
    return __builtin_bit_cast(u16, __float2bfloat16(x));
}
__device__ __forceinline__ float bf2f(u16 u) {
    return __bfloat162float(__builtin_bit_cast(__hip_bfloat16, u));
}
__device__ __forceinline__ f32x16 mfma_b(bf16x8 a, bf16x8 b, f32x16 c) {
    return __builtin_amdgcn_mfma_f32_32x32x16_bf16(a, b, c, 0, 0, 0);
}
// async 16B/lane global -> LDS (LDS dest = wave-uniform base + lane*16)
__device__ __forceinline__ void gl_lds16(const u16* g, u16* l) {
    __builtin_amdgcn_global_load_lds(
        (const __attribute__((address_space(1))) void*)(g),
        (__attribute__((address_space(3))) void*)(l), 16, 0, 0);
}

// ---------------------------------------------------------------- prep
__global__ void prep_kernel(const float* __restrict__ t1, const float* __restrict__ t2,
                            const float* __restrict__ t1c,
                            const float* __restrict__ W1, const float* __restrict__ W2,
                            const float* __restrict__ W3,
                            const float* __restrict__ Wo1, const float* __restrict__ Wo2,
                            const float* __restrict__ Wo3,
                            u16* __restrict__ tA, u16* __restrict__ WqkvT,
                            u16* __restrict__ WoT)
{
    int idx = blockIdx.x * blockDim.x + threadIdx.x;
    const int TA_N = 3 * N_TOK * KPAD;
    const int WQ_N = 3 * OUT3 * KPAD;
    const int WO_N = 3 * DIMF * RDIM;
    if (idx < TA_N) {
        int m = idx / (N_TOK * KPAD);
        int rem = idx - m * (N_TOK * KPAD);
        int row = rem / KPAD;
        int col = rem - row * KPAD;
        const float* t = (m == 0) ? t1 : (m == 1) ? t2 : t1c;
        tA[idx] = (col < DIMF) ? f2bf(t[row * DIMF + col]) : (u16)0;
    } else if (idx < TA_N + WQ_N) {
        int i = idx - TA_N;
        int m = i / (OUT3 * KPAD);
        int rem = i - m * (OUT3 * KPAD);
        int n = rem / KPAD;
        int c = rem - n * KPAD;
        const float* W = (m == 0) ? W1 : (m == 1) ? W2 : W3;
        WqkvT[i] = (c < DIMF) ? f2bf(W[c * OUT3 + n]) : (u16)0;
    } else if (idx < TA_N + WQ_N + WO_N) {
        int i = idx - TA_N - WQ_N;
        int m = i / (DIMF * RDIM);
        int rem = i - m * (DIMF * RDIM);
        int n = rem / RDIM;
        int c = rem - n * RDIM;
        const float* W = (m == 0) ? Wo1 : (m == 1) ? Wo2 : Wo3;
        WoT[i] = f2bf(W[c * DIMF + n]);
    }
}

// ---------------------------------------------------------------- QKV gemm
__global__ __launch_bounds__(256, 1) void qkv_gemm(
    const u16* __restrict__ tA, const u16* __restrict__ WqkvT,
    const float* __restrict__ b1, const float* __restrict__ b2, const float* __restrict__ b3,
    u16* __restrict__ qbuf, u16* __restrict__ kbuf, u16* __restrict__ vT)
{
    const int mt = blockIdx.x, nt = blockIdx.y, mod = blockIdx.z;
    const u16* A = tA + mod * (N_TOK * KPAD);
    const u16* B = WqkvT + mod * (OUT3 * KPAD);
    const float* bias = (mod == 0) ? b1 : (mod == 1) ? b2 : b3;

    __shared__ alignas(16) u16 Al[128 * 40];
    __shared__ alignas(16) u16 Bl[128 * 40];

    const int tid = threadIdx.x;
    const int lane = tid & 63;
    const int w = tid >> 6;
    const int wm = w & 1, wn = w >> 1;
    const int l31 = lane & 31, h = lane >> 5;

    f32x16 acc[2][2];
#pragma unroll
    for (int i = 0; i < 2; i++)
#pragma unroll
        for (int j = 0; j < 2; j++)
#pragma unroll
            for (int r = 0; r < 16; r++) acc[i][j][r] = 0.f;

    for (int kt = 0; kt < KPAD / 32; kt++) {
#pragma unroll
        for (int it = 0; it < 2; it++) {
            int idx = it * 256 + tid;
            int row = idx >> 2;
            int c8 = (idx & 3) * 8;
            uint4 va = *reinterpret_cast<const uint4*>(&A[(mt * 128 + row) * KPAD + kt * 32 + c8]);
            *reinterpret_cast<uint4*>(&Al[row * 40 + c8]) = va;
            uint4 vb = *reinterpret_cast<const uint4*>(&B[(nt * 128 + row) * KPAD + kt * 32 + c8]);
            *reinterpret_cast<uint4*>(&Bl[row * 40 + c8]) = vb;
        }
        __syncthreads();
#pragma unroll
        for (int kc = 0; kc < 2; kc++) {
            bf16x8 af[2], bfr[2];
#pragma unroll
            for (int mr = 0; mr < 2; mr++)
                af[mr] = ld_frag(&Al[(wm * 64 + mr * 32 + l31) * 40 + kc * 16 + h * 8]);
#pragma unroll
            for (int nr = 0; nr < 2; nr++)
                bfr[nr] = ld_frag(&Bl[(wn * 64 + nr * 32 + l31) * 40 + kc * 16 + h * 8]);
#pragma unroll
            for (int mr = 0; mr < 2; mr++)
#pragma unroll
                for (int nr = 0; nr < 2; nr++)
                    acc[mr][nr] = mfma_b(af[mr], bfr[nr], acc[mr][nr]);
        }
        __syncthreads();
    }

    u16* qb = qbuf + mod * (N_TOK * OUTD);
    u16* kb = kbuf + mod * (N_TOK * OUTD);
    u16* vb = vT + mod * (OUTD * N_TOK);
#pragma unroll
    for (int mr = 0; mr < 2; mr++)
#pragma unroll
        for (int nr = 0; nr < 2; nr++)
#pragma unroll
            for (int r = 0; r < 16; r++) {
                int row = mt * 128 + wm * 64 + mr * 32 + (r & 3) + 8 * (r >> 2) + 4 * h;
                int col = nt * 128 + wn * 64 + nr * 32 + l31;
                u16 bv = f2bf(acc[mr][nr][r] + bias[col]);
                int cs = col >> 8, cc = col & 255;
                if (cs == 0)      qb[row * OUTD + cc] = bv;
                else if (cs == 1) kb[row * OUTD + cc] = bv;
                else              vb[cc * N_TOK + row] = bv;   // v transposed
            }
}

// ---------------------------------------------------------------- attention
// Block: 256 thr = 4 waves, 128 q rows (32/wave). Double-buffered async
// staging: 32-key K/V tile stored in FRAGMENT order (frag f at f*1024B +
// lane*16B) via global_load_lds; waves 0/1 stage K frags, 2/3 stage V frags.
// One barrier per tile; next tile's loads overlap current tile's MFMAs.
// S^T = K Q^T, P^T built in registers via half-wave shuffles, O^T = V^T P^T.
// VGPR note: must stay <=128 arch VGPRs (+128 acc) for 8 waves/CU;
// do NOT raise min-waves (R3: spill) and do NOT add register prefetch.
__global__ __launch_bounds__(256, 2) void attn_kernel(
    const u16* __restrict__ qbuf, const u16* __restrict__ kbuf,
    const u16* __restrict__ vT, u16* __restrict__ Opart, float* __restrict__ lpart)
{
    const int qt = blockIdx.x;   // 0..31  (128-row q tile)
    const int g  = blockIdx.y;   // 0..5
    const int c  = blockIdx.z;   // 0..NCHUNK-1
    const int kv = g >> 1;
    const int mn = (kv == 0) ? 1 : 0;
    const int mx = (kv == 2) ? 1 : 2;
    const int qm = (g & 1) ? mx : mn;

    const u16* Qg = qbuf + qm * (N_TOK * OUTD);
    const u16* Kg = kbuf + kv * (N_TOK * OUTD);
    const u16* Vg = vT + kv * (OUTD * N_TOK);
    u16* Op = Opart + ((size_t)(c * 6 + g) * N_TOK + qt * 128) * OUTD;
    float* lp = lpart + (c * 6 + g) * N_TOK + qt * 128;

    // 2 buffers x 32 frags x 512 u16 (1KB per frag: 64 lanes x 16B)
    __shared__ alignas(16) u16 Fbuf[2][32 * 512];

    const int tid = threadIdx.x;
    const int lane = tid & 63;
    const int w = tid >> 6;           // 0..3
    const int l31 = lane & 31, h = lane >> 5;
    const int q0 = qt * 128 + w * 32;

    // ---- stage helper: wave w stages frags 8w..8w+7 of tile at k0
    auto stage = [&](int k0, u16* dst) {
        if (w < 2) {
#pragma unroll
            for (int fi = 0; fi < 8; fi++) {
                int dc = w * 8 + fi;
                gl_lds16(&Kg[(k0 + l31) * OUTD + dc * 16 + h * 8], dst + dc * 512);
            }
        } else {
#pragma unroll
            for (int fi = 0; fi < 8; fi++) {
                int f = (w - 2) * 8 + fi;           // 0..15
                int nb = f >> 1, half = f & 1;
                gl_lds16(&Vg[(nb * 32 + l31) * N_TOK + k0 + half * 16 + h * 8],
                         dst + (16 + f) * 512);
            }
        }
    };

    const int k0base = c * (N_TOK / NCHUNK);

    // prologue: stage tile 0, load Q frags (overlapping VMEM)
    stage(k0base, Fbuf[0]);

    bf16x8 qf[16];
#pragma unroll
    for (int dc = 0; dc < 16; dc++)
        qf[dc] = ld_frag(&Qg[(q0 + l31) * OUTD + dc * 16 + h * 8]);

    f32x16 Oacc[8];
#pragma unroll
    for (int nb = 0; nb < 8; nb++)
#pragma unroll
        for (int r = 0; r < 16; r++) Oacc[nb][r] = 0.f;
    float lsum = 0.f;

    __syncthreads();   // drains vmcnt: tile 0 resident

    for (int kt = 0; kt < KTILES; kt++) {
        const int p = kt & 1;
        if (kt + 1 < KTILES) stage(k0base + (kt + 1) * 32, Fbuf[p ^ 1]);
        const u16* FB = Fbuf[p];

        // S^T[key][q] = K Q^T   (16 frag reads, conflict-free lane*16)
        f32x16 S;
#pragma unroll
        for (int r = 0; r < 16; r++) S[r] = 0.f;
#pragma unroll
        for (int dc = 0; dc < 16; dc++) {
            bf16x8 kf = ld_frag(&FB[dc * 512 + lane * 8]);
            S = mfma_b(kf, qf[dc], S);
        }

        // P^T = exp(S^T - 16); per-lane partial of column sums
        float e[16];
#pragma unroll
        for (int r = 0; r < 16; r++) { e[r] = __expf(S[r] - SHIFT); lsum += e[r]; }
        u32 pk[8];
#pragma unroll
        for (int i = 0; i < 8; i++)
            pk[i] = (u32)f2bf(e[2 * i]) | ((u32)f2bf(e[2 * i + 1]) << 16);
        u32 x[8];
#pragma unroll
        for (int i = 0; i < 8; i++)
            x[i] = (u32)__shfl_xor((int)pk[i], 32, 64);
        uint4 b0, b1;
        b0.x = h ? x[2] : pk[0]; b0.y = h ? x[3] : pk[1];
        b0.z = h ? pk[2] : x[0]; b0.w = h ? pk[3] : x[1];
        b1.x = h ? x[6] : pk[4]; b1.y = h ? x[7] : pk[5];
        b1.z = h ? pk[6] : x[4]; b1.w = h ? pk[7] : x[5];
        bf16x8 pb0 = __builtin_bit_cast(bf16x8, b0);
        bf16x8 pb1 = __builtin_bit_cast(bf16x8, b1);

        // O^T[d][q] += V^T[d][k] P^T[k][q]
#pragma unroll
        for (int nb = 0; nb < 8; nb++) {
            bf16x8 vf0 = ld_frag(&FB[(16 + 2 * nb) * 512 + lane * 8]);
            bf16x8 vf1 = ld_frag(&FB[(17 + 2 * nb) * 512 + lane * 8]);
            Oacc[nb] = mfma_b(vf0, pb0, Oacc[nb]);
            Oacc[nb] = mfma_b(vf1, pb1, Oacc[nb]);
        }
        __syncthreads();   // waves done with FB; tile kt+1 loads drained
    }

    // l partial: combine h-halves (column q = l31)
    lsum += __shfl_xor(lsum, 32, 64);
    if (lane < 32) lp[w * 32 + lane] = lsum;

    // transpose O^T -> [q][d] through wave-private LDS scratch, store bf16
    float* Tb = reinterpret_cast<float*>(&Fbuf[0][0]) + w * (32 * 33);
#pragma unroll
    for (int nb = 0; nb < 8; nb++) {
#pragma unroll
        for (int r = 0; r < 16; r++)
            Tb[((r & 3) + 8 * (r >> 2) + 4 * h) * 33 + l31] = Oacc[nb][r];
        __builtin_amdgcn_s_waitcnt(0);  // lgkm drain before re-read (wave-private)
#pragma unroll
        for (int qq = 0; qq < 16; qq++) {
            float v = Tb[l31 * 33 + qq * 2 + h];
            Op[(w * 32 + qq * 2 + h) * OUTD + nb * 32 + l31] = f2bf(v);
        }
        __builtin_amdgcn_s_waitcnt(0);
    }
}

// ---------------------------------------------------------------- combine
// o = sum(O_c)/sum(l_c) + k_residual -> rbuf bf16 [qm][q][slot*256+d]
__global__ __launch_bounds__(256, 1) void combine_kernel(
    const u16* __restrict__ Opart, const float* __restrict__ lpart,
    const u16* __restrict__ kbuf, u16* __restrict__ rbuf)
{
    const int q = blockIdx.x;
    const int g = blockIdx.y;
    const int d = threadIdx.x;
    const int kv = g >> 1;
    const int mn = (kv == 0) ? 1 : 0;
    const int mx = (kv == 2) ? 1 : 2;
    const int qm = (g & 1) ? mx : mn;
    const int sm = (qm == 0) ? 1 : 0;
    const int slot = (kv == sm) ? 0 : 1;

    float o = 0.f, l = 0.f;
#pragma unroll
    for (int c = 0; c < NCHUNK; c++) {
        o += bf2f(Opart[((size_t)(c * 6 + g) * N_TOK + q) * OUTD + d]);
        l += lpart[(c * 6 + g) * N_TOK + q];
    }
    float res = o / l + bf2f(kbuf[qm * (N_TOK * OUTD) + q * OUTD + d]);
    rbuf[qm * (size_t)(N_TOK * RDIM) + q * RDIM + slot * OUTD + d] = f2bf(res);
}

// ---------------------------------------------------------------- out proj
__global__ __launch_bounds__(256, 1) void proj_gemm(
    const u16* __restrict__ rbuf, const u16* __restrict__ WoT,
    const float* __restrict__ bo1, const float* __restrict__ bo2, const float* __restrict__ bo3,
    const float* __restrict__ t1, const float* __restrict__ t2, const float* __restrict__ t1c,
    float* __restrict__ feat)
{
    const int mt = blockIdx.x, nt = blockIdx.y, mod = blockIdx.z;
    const u16* A = rbuf + mod * (N_TOK * RDIM);
    const u16* B = WoT + mod * (DIMF * RDIM);
    const float* bias = (mod == 0) ? bo1 : (mod == 1) ? bo2 : bo3;
    const float* tres = (mod == 0) ? t1 : (mod == 1) ? t2 : t1c;

    __shared__ alignas(16) u16 Al[128 * 40];
    __shared__ alignas(16) u16 Bl[128 * 40];

    const int tid = threadIdx.x;
    const int lane = tid & 63;
    const int w = tid >> 6;
    const int wm = w & 1, wn = w >> 1;
    const int l31 = lane & 31, h = lane >> 5;

    f32x16 acc[2][2];
#pragma unroll
    for (int i = 0; i < 2; i++)
#pragma unroll
        for (int j = 0; j < 2; j++)
#pragma unroll
            for (int r = 0; r < 16; r++) acc[i][j][r] = 0.f;

    for (int kt = 0; kt < RDIM / 32; kt++) {
#pragma unroll
        for (int it = 0; it < 2; it++) {
            int idx = it * 256 + tid;
            int row = idx >> 2;
            int c8 = (idx & 3) * 8;
            uint4 va = *reinterpret_cast<const uint4*>(&A[(mt * 128 + row) * RDIM + kt * 32 + c8]);
            *reinterpret_cast<uint4*>(&Al[row * 40 + c8]) = va;
            int n = nt * 128 + row;
            uint4 vb;
            if (n < DIMF) vb = *reinterpret_cast<const uint4*>(&B[n * RDIM + kt * 32 + c8]);
            else { vb.x = vb.y = vb.z = vb.w = 0u; }
            *reinterpret_cast<uint4*>(&Bl[row * 40 + c8]) = vb;
        }
        __syncthreads();
#pragma unroll
        for (int kc = 0; kc < 2; kc++) {
            bf16x8 af[2], bfr[2];
#pragma unroll
            for (int mr = 0; mr < 2; mr++)
                af[mr] = ld_frag(&Al[(wm * 64 + mr * 32 + l31) * 40 + kc * 16 + h * 8]);
#pragma unroll
            for (int nr = 0; nr < 2; nr++)
                bfr[nr] = ld_frag(&Bl[(wn * 64 + nr * 32 + l31) * 40 + kc * 16 + h * 8]);
#pragma unroll
            for (int mr = 0; mr < 2; mr++)
#pragma unroll
                for (int nr = 0; nr < 2; nr++)
                    acc[mr][nr] = mfma_b(af[mr], bfr[nr], acc[mr][nr]);
        }
        __syncthreads();
    }

#pragma unroll
    for (int mr = 0; mr < 2; mr++)
#pragma unroll
        for (int nr = 0; nr < 2; nr++)
#pragma unroll
            for (int r = 0; r < 16; r++) {
                int row = mt * 128 + wm * 64 + mr * 32 + (r & 3) + 8 * (r >> 2) + 4 * h;
                int col = nt * 128 + wn * 64 + nr * 32 + l31;
                if (col < DIMF) {
                    float v = acc[mr][nr][r] + bias[col] + tres[row * DIMF + col];
                    feat[row * FDIM + mod * DIMF + col] = v;
                }
            }
}

// ---------------------------------------------------------------- LN + head
__global__ __launch_bounds__(256, 1) void ln_head(
    const float* __restrict__ feat, const float* __restrict__ gam,
    const float* __restrict__ bet, const float* __restrict__ Wh,
    const float* __restrict__ bh, float* __restrict__ out)
{
    const int row = blockIdx.x;
    const float* x = feat + row * FDIM;
    const int tid = threadIdx.x;
    float v[7];
    float s = 0.f, ss = 0.f;
#pragma unroll
    for (int i = 0; i < 7; i++) {
        int idx = tid + i * 256;
        float val = (idx < FDIM) ? x[idx] : 0.f;
        v[i] = val; s += val; ss += val * val;
    }
#pragma unroll
    for (int m = 1; m < 64; m <<= 1) { s += __shfl_xor(s, m, 64); ss += __shfl_xor(ss, m, 64); }
    __shared__ float red[8];
    const int w = tid >> 6, lane = tid & 63;
    if (lane == 0) { red[w] = s; red[4 + w] = ss; }
    __syncthreads();
    s = red[0] + red[1] + red[2] + red[3];
    ss = red[4] + red[5] + red[6] + red[7];
    const float mu = s / (float)FDIM;
    const float var = ss / (float)FDIM - mu * mu;
    const float rstd = rsqrtf(var + 1e-5f);
    float a0 = 0.f, a1 = 0.f;
#pragma unroll
    for (int i = 0; i < 7; i++) {
        int idx = tid + i * 256;
        if (idx < FDIM) {
            float nv = (v[i] - mu) * rstd * gam[idx] + bet[idx];
            a0 += nv * Wh[idx * 2];
            a1 += nv * Wh[idx * 2 + 1];
        }
    }
#pragma unroll
    for (int m = 1; m < 64; m <<= 1) { a0 += __shfl_xor(a0, m, 64); a1 += __shfl_xor(a1, m, 64); }
    __shared__ float red2[8];
    if (lane == 0) { red2[w] = a0; red2[4 + w] = a1; }
    __syncthreads();
    if (tid == 0) {
        out[row * 2 + 0] = red2[0] + red2[1] + red2[2] + red2[3] + bh[0];
        out[row * 2 + 1] = red2[4] + red2[5] + red2[6] + red2[7] + bh[1];
    }
}

// ---------------------------------------------------------------- launch
extern "C" void kernel_launch(void* const* d_in, const int* in_sizes, int n_in,
                              void* d_out, int out_size, void* d_ws, size_t ws_size,
                              hipStream_t stream)
{
    const float* t1    = (const float*)d_in[0];
    const float* t2    = (const float*)d_in[1];
    const float* t1c   = (const float*)d_in[2];
    const float* Wqkv1 = (const float*)d_in[3];
    const float* bqkv1 = (const float*)d_in[4];
    const float* Wqkv2 = (const float*)d_in[5];
    const float* bqkv2 = (const float*)d_in[6];
    const float* Wqkv3 = (const float*)d_in[7];
    const float* bqkv3 = (const float*)d_in[8];
    const float* Wo1   = (const float*)d_in[9];
    const float* bo1   = (const float*)d_in[10];
    const float* Wo2   = (const float*)d_in[11];
    const float* bo2   = (const float*)d_in[12];
    const float* Wo3   = (const float*)d_in[13];
    const float* bo3   = (const float*)d_in[14];
    const float* ln_g  = (const float*)d_in[15];
    const float* ln_b  = (const float*)d_in[16];
    const float* Wh    = (const float*)d_in[17];
    const float* bh    = (const float*)d_in[18];

    char* ws = (char*)d_ws;
    size_t off = 0;
    u16* tA    = (u16*)(ws + off); off += (size_t)3 * N_TOK * KPAD * 2;
    u16* WqkvT = (u16*)(ws + off); off += (size_t)3 * OUT3 * KPAD * 2;
    u16* WoT   = (u16*)(ws + off); off += (size_t)3 * DIMF * RDIM * 2;
    u16* qbuf  = (u16*)(ws + off); off += (size_t)3 * N_TOK * OUTD * 2;
    u16* kbuf  = (u16*)(ws + off); off += (size_t)3 * N_TOK * OUTD * 2;
    u16* vT    = (u16*)(ws + off); off += (size_t)3 * OUTD * N_TOK * 2;
    u16* rbuf  = (u16*)(ws + off); off += (size_t)3 * N_TOK * RDIM * 2;
    u16* Opart = (u16*)(ws + off); off += (size_t)NCHUNK * 6 * N_TOK * OUTD * 2;
    float* lpart = (float*)(ws + off); off += (size_t)NCHUNK * 6 * N_TOK * 4;

    float* out  = (float*)d_out;
    float* feat = out + N_TOK * 2;

    const int prep_total = 3 * N_TOK * KPAD + 3 * OUT3 * KPAD + 3 * DIMF * RDIM;
    prep_kernel<<<(prep_total + 255) / 256, 256, 0, stream>>>(
        t1, t2, t1c, Wqkv1, Wqkv2, Wqkv3, Wo1, Wo2, Wo3, tA, WqkvT, WoT);

    qkv_gemm<<<dim3(32, 6, 3), 256, 0, stream>>>(
        tA, WqkvT, bqkv1, bqkv2, bqkv3, qbuf, kbuf, vT);

    attn_kernel<<<dim3(32, 6, NCHUNK), 256, 0, stream>>>(qbuf, kbuf, vT, Opart, lpart);

    combine_kernel<<<dim3(N_TOK, 6), 256, 0, stream>>>(Opart, lpart, kbuf, rbuf);

    proj_gemm<<<dim3(32, 5, 3), 256, 0, stream>>>(
        rbuf, WoT, bo1, bo2, bo3, t1, t2, t1c, feat);

    ln_head<<<4096, 256, 0, stream>>>(feat, ln_g, ln_b, Wh, bh, out);
}